// Round 1
// baseline (189.425 us; speedup 1.0000x reference)
//
#include <hip/hip_runtime.h>
#include <hip/hip_bf16.h>
#include <math.h>

#define C_IN 256
#define CC 128
#define NDEPTH 88
#define HW 2816            // 32*88
#define NB 12
#define TILE 64            // hw columns per workgroup
#define NTILES 44          // 2816/64
#define BEV_OFF   ((size_t)8650752)   // 12*256*2816
#define LOG_OFF   ((size_t)8650752)
#define PROB_OFF  ((size_t)11624448)  // + 12*88*2816

typedef __attribute__((ext_vector_type(8))) short bf16x8;
typedef __attribute__((ext_vector_type(4))) float f32x4;

__device__ __forceinline__ unsigned short f2bf(float f) {
    unsigned int u = __float_as_uint(f);
    unsigned int r = (u + 0x7fffu + ((u >> 16) & 1u)) >> 16;
    return (unsigned short)r;
}
__device__ __forceinline__ unsigned int pack2(float a, float b) {
    return (unsigned int)f2bf(a) | ((unsigned int)f2bf(b) << 16);
}

// ---------------- prep: weights->bf16 (padded), BN fold ----------------
__global__ void prep_kernel(const float* __restrict__ dnet_w,
                            const float* __restrict__ proj_w,
                            const float* __restrict__ gamma,
                            const float* __restrict__ beta,
                            const float* __restrict__ mean,
                            const float* __restrict__ var,
                            unsigned short* __restrict__ w1d,   // [96][256]
                            unsigned short* __restrict__ w1t,   // [128][256]
                            unsigned short* __restrict__ projb, // [256][128]
                            float* __restrict__ scale,
                            float* __restrict__ shift) {
    const int tid = blockIdx.x * blockDim.x + threadIdx.x;
    const int total = 96 * 256 + 128 * 256 + 256 * 128;
    for (int idx = tid; idx < total; idx += gridDim.x * blockDim.x) {
        if (idx < 96 * 256) {
            int o = idx >> 8, c = idx & 255;
            w1d[idx] = (o < NDEPTH) ? f2bf(dnet_w[o * 256 + c]) : (unsigned short)0;
        } else if (idx < 96 * 256 + 128 * 256) {
            int j = idx - 96 * 256;
            w1t[j] = f2bf(dnet_w[(NDEPTH + (j >> 8)) * 256 + (j & 255)]);
        } else {
            int j = idx - 96 * 256 - 128 * 256;
            projb[j] = f2bf(proj_w[j]);
        }
    }
    if (tid < 256) {
        float sc = gamma[tid] * rsqrtf(var[tid] + 1e-5f);
        scale[tid] = sc;
        shift[tid] = beta[tid] - mean[tid] * sc;
    }
}

// ---------------- fused main kernel ----------------
__global__ __launch_bounds__(256)
void fused_kernel(const float* __restrict__ x,
                  const float* __restrict__ dnet_b,
                  const unsigned short* __restrict__ w1d,
                  const unsigned short* __restrict__ w1t,
                  const unsigned short* __restrict__ projb,
                  const float* __restrict__ scale,
                  const float* __restrict__ shift,
                  float* __restrict__ out) {
    // xs: x-tile transposed [hw=64][c=256] bf16, XOR-swizzled in 16B chunks
    __shared__ __align__(16) unsigned short xs[64 * 256];
    // per-wave tran tile [hw=16][k=128] bf16, XOR-swizzled
    __shared__ __align__(16) unsigned short trs[4][16 * 128];

    const int bid = blockIdx.x;
    const int n   = bid / NTILES;
    const int hw0 = (bid % NTILES) * TILE;
    const int t    = threadIdx.x;
    const int lane = t & 63;
    const int wv   = t >> 6;          // wave id 0..3

    // ---- stage x tile into LDS (transpose to [hw][c], bf16) ----
    {
        const int hwl = t & 63;
        const int cg  = t >> 6;       // 0..3
        const float* xb = x + (size_t)n * C_IN * HW + hw0 + hwl;
        #pragma unroll
        for (int cb = 0; cb < 256; cb += 32) {
            const int c0 = cb + cg * 8;
            float f[8];
            #pragma unroll
            for (int j = 0; j < 8; ++j) f[j] = xb[(size_t)(c0 + j) * HW];
            uint4 v;
            v.x = pack2(f[0], f[1]);
            v.y = pack2(f[2], f[3]);
            v.z = pack2(f[4], f[5]);
            v.w = pack2(f[6], f[7]);
            const int csw = (c0 >> 3) ^ (hwl & 7);
            *reinterpret_cast<uint4*>(&xs[hwl * 256 + csw * 8]) = v;
        }
    }
    __syncthreads();

    const int g = lane >> 4;          // 0..3
    const int m = lane & 15;
    const int hwb  = wv * 16;         // wave's hw base inside tile
    const int brow = hwb + m;         // xs row this lane reads (== its D column)

    // ---- GEMM1: dc[o][hw] = sum_c W1[o][c] * x[c][hw] ----
    f32x4 accd[6], acct[8];
    #pragma unroll
    for (int i = 0; i < 6; ++i) accd[i] = (f32x4){0.f, 0.f, 0.f, 0.f};
    #pragma unroll
    for (int i = 0; i < 8; ++i) acct[i] = (f32x4){0.f, 0.f, 0.f, 0.f};

    #pragma unroll
    for (int ks = 0; ks < 8; ++ks) {
        const int k0 = ks * 32;
        const int csw = ((k0 >> 3) + g) ^ (brow & 7);
        bf16x8 b = *reinterpret_cast<const bf16x8*>(&xs[brow * 256 + csw * 8]);
        #pragma unroll
        for (int dt = 0; dt < 6; ++dt) {
            bf16x8 a = *reinterpret_cast<const bf16x8*>(&w1d[(dt * 16 + m) * 256 + k0 + g * 8]);
            accd[dt] = __builtin_amdgcn_mfma_f32_16x16x32_bf16(a, b, accd[dt], 0, 0, 0);
        }
        #pragma unroll
        for (int tt = 0; tt < 8; ++tt) {
            bf16x8 a = *reinterpret_cast<const bf16x8*>(&w1t[(tt * 16 + m) * 256 + k0 + g * 8]);
            acct[tt] = __builtin_amdgcn_mfma_f32_16x16x32_bf16(a, b, acct[tt], 0, 0, 0);
        }
    }

    // ---- write tran (+bias) to per-wave LDS as bf16 (frees acct) ----
    {
        unsigned short* tw = &trs[wv][0];
        #pragma unroll
        for (int tt = 0; tt < 8; ++tt) {
            float v0 = acct[tt][0] + dnet_b[NDEPTH + tt * 16 + g * 4 + 0];
            float v1 = acct[tt][1] + dnet_b[NDEPTH + tt * 16 + g * 4 + 1];
            float v2 = acct[tt][2] + dnet_b[NDEPTH + tt * 16 + g * 4 + 2];
            float v3 = acct[tt][3] + dnet_b[NDEPTH + tt * 16 + g * 4 + 3];
            const int col = tt * 16 + g * 4;
            const int csw = (col >> 3) ^ (m & 7);
            uint2 pkd;
            pkd.x = pack2(v0, v1);
            pkd.y = pack2(v2, v3);
            *reinterpret_cast<uint2*>(&tw[m * 128 + csw * 8 + (g & 1) * 4]) = pkd;
        }
    }

    // ---- depth: bias, softmax over o (cross-lane ^16,^32), s, stores ----
    const int hwcol = hw0 + hwb + m;   // global hw of this lane's D column
    float dv[6][4], ev[6][4];
    float mx = -1e30f;
    #pragma unroll
    for (int dt = 0; dt < 6; ++dt) {
        #pragma unroll
        for (int r = 0; r < 4; ++r) {
            const int o = dt * 16 + g * 4 + r;
            float v = accd[dt][r] + ((o < NDEPTH) ? dnet_b[o] : 0.f);
            dv[dt][r] = v;
            if (o < NDEPTH) mx = fmaxf(mx, v);
        }
    }
    mx = fmaxf(mx, __shfl_xor(mx, 16));
    mx = fmaxf(mx, __shfl_xor(mx, 32));
    float sum = 0.f;
    #pragma unroll
    for (int dt = 0; dt < 6; ++dt) {
        #pragma unroll
        for (int r = 0; r < 4; ++r) {
            const int o = dt * 16 + g * 4 + r;
            float e = (o < NDEPTH) ? __expf(dv[dt][r] - mx) : 0.f;
            ev[dt][r] = e;
            sum += e;
        }
    }
    sum += __shfl_xor(sum, 16);
    sum += __shfl_xor(sum, 32);
    const float inv = 1.0f / sum;

    float sp = 0.f;
    #pragma unroll
    for (int dt = 0; dt < 6; ++dt) {
        #pragma unroll
        for (int r = 0; r < 4; ++r) {
            const int o = dt * 16 + g * 4 + r;
            if (o < NDEPTH)
                sp += ev[dt][r] * inv * ((1.f + (float)o * (44.f / 87.f)) * (1.f / 23.f));
        }
    }
    sp += __shfl_xor(sp, 16);
    sp += __shfl_xor(sp, 32);   // s for this lane's hw column

    {
        float* lg = out + LOG_OFF  + (size_t)n * NDEPTH * HW + hwcol;
        float* pb = out + PROB_OFF + (size_t)n * NDEPTH * HW + hwcol;
        #pragma unroll
        for (int dt = 0; dt < 6; ++dt) {
            #pragma unroll
            for (int r = 0; r < 4; ++r) {
                const int o = dt * 16 + g * 4 + r;
                if (o < NDEPTH) {
                    lg[(size_t)o * HW] = dv[dt][r];
                    pb[(size_t)o * HW] = ev[dt][r] * inv;
                }
            }
        }
    }
    __syncthreads();   // conservative: order trs writes vs reads

    // ---- GEMM2: out[cc][hw] = sum_k proj[cc][k] * tran[k][hw] ----
    f32x4 acc2[16];
    #pragma unroll
    for (int i = 0; i < 16; ++i) acc2[i] = (f32x4){0.f, 0.f, 0.f, 0.f};
    {
        const unsigned short* tw = &trs[wv][0];
        #pragma unroll
        for (int ks = 0; ks < 4; ++ks) {
            const int k0 = ks * 32;
            const int csw = ((k0 >> 3) + g) ^ (m & 7);
            bf16x8 b = *reinterpret_cast<const bf16x8*>(&tw[m * 128 + csw * 8]);
            #pragma unroll
            for (int ct = 0; ct < 16; ++ct) {
                bf16x8 a = *reinterpret_cast<const bf16x8*>(&projb[(ct * 16 + m) * 128 + k0 + g * 8]);
                acc2[ct] = __builtin_amdgcn_mfma_f32_16x16x32_bf16(a, b, acc2[ct], 0, 0, 0);
            }
        }
    }

    // ---- epilogue: BN + exact GELU + *s, store bev ----
    {
        float* bev = out + (size_t)n * C_IN * HW + hwcol;
        #pragma unroll
        for (int ct = 0; ct < 16; ++ct) {
            #pragma unroll
            for (int r = 0; r < 4; ++r) {
                const int cc = ct * 16 + g * 4 + r;
                float v  = acc2[ct][r] * scale[cc] + shift[cc];
                float ge = 0.5f * v * (1.f + erff(v * 0.70710678118f));
                bev[(size_t)cc * HW] = ge * sp;
            }
        }
    }
}

extern "C" void kernel_launch(void* const* d_in, const int* in_sizes, int n_in,
                              void* d_out, int out_size, void* d_ws, size_t ws_size,
                              hipStream_t stream) {
    const float* x      = (const float*)d_in[0];
    const float* dnet_w = (const float*)d_in[1];
    const float* dnet_b = (const float*)d_in[2];
    const float* proj_w = (const float*)d_in[3];
    const float* gamma  = (const float*)d_in[4];
    const float* beta   = (const float*)d_in[5];
    const float* mean   = (const float*)d_in[6];
    const float* var    = (const float*)d_in[7];
    float* out = (float*)d_out;

    char* ws = (char*)d_ws;
    unsigned short* w1d   = (unsigned short*)ws;                         // 96*256*2  = 49152 B
    unsigned short* w1t   = (unsigned short*)(ws + 49152);               // 128*256*2 = 65536 B
    unsigned short* projb = (unsigned short*)(ws + 49152 + 65536);       // 256*128*2 = 65536 B
    float* scale = (float*)(ws + 49152 + 65536 + 65536);
    float* shift = scale + 256;

    prep_kernel<<<96, 256, 0, stream>>>(dnet_w, proj_w, gamma, beta, mean, var,
                                        w1d, w1t, projb, scale, shift);
    fused_kernel<<<NB * NTILES, 256, 0, stream>>>(x, dnet_b, w1d, w1t, projb,
                                                  scale, shift, out);
}

// Round 2
// 160.967 us; speedup vs baseline: 1.1768x; 1.1768x over previous
//
#include <hip/hip_runtime.h>
#include <hip/hip_bf16.h>
#include <math.h>

#define C_IN 256
#define CC 128
#define NDEPTH 88
#define HW 2816            // 32*88
#define NB 12
#define TILE 32            // hw columns per workgroup (2 strips of 16)
#define NTILES 88          // 2816/32
#define LOG_OFF   ((size_t)8650752)   // 12*256*2816
#define PROB_OFF  ((size_t)11624448)  // + 12*88*2816

typedef __attribute__((ext_vector_type(8))) short bf16x8;
typedef __attribute__((ext_vector_type(4))) float f32x4;

__device__ __forceinline__ unsigned short f2bf(float f) {
    unsigned int u = __float_as_uint(f);
    unsigned int r = (u + 0x7fffu + ((u >> 16) & 1u)) >> 16;
    return (unsigned short)r;
}
__device__ __forceinline__ unsigned int pack2(float a, float b) {
    return (unsigned int)f2bf(a) | ((unsigned int)f2bf(b) << 16);
}

// ---------------- prep: weights->bf16 (padded), BN fold ----------------
__global__ void prep_kernel(const float* __restrict__ dnet_w,
                            const float* __restrict__ proj_w,
                            const float* __restrict__ gamma,
                            const float* __restrict__ beta,
                            const float* __restrict__ mean,
                            const float* __restrict__ var,
                            unsigned short* __restrict__ w1d,   // [96][256]
                            unsigned short* __restrict__ w1t,   // [128][256]
                            unsigned short* __restrict__ projb, // [256][128]
                            float* __restrict__ scale,
                            float* __restrict__ shift) {
    const int tid = blockIdx.x * blockDim.x + threadIdx.x;
    const int total = 96 * 256 + 128 * 256 + 256 * 128;
    for (int idx = tid; idx < total; idx += gridDim.x * blockDim.x) {
        if (idx < 96 * 256) {
            int o = idx >> 8, c = idx & 255;
            w1d[idx] = (o < NDEPTH) ? f2bf(dnet_w[o * 256 + c]) : (unsigned short)0;
        } else if (idx < 96 * 256 + 128 * 256) {
            int j = idx - 96 * 256;
            w1t[j] = f2bf(dnet_w[(NDEPTH + (j >> 8)) * 256 + (j & 255)]);
        } else {
            int j = idx - 96 * 256 - 128 * 256;
            projb[j] = f2bf(proj_w[j]);
        }
    }
    if (tid < 256) {
        float sc = gamma[tid] * rsqrtf(var[tid] + 1e-5f);
        scale[tid] = sc;
        shift[tid] = beta[tid] - mean[tid] * sc;
    }
}

// ---------------- fused main kernel ----------------
// 256 threads = 4 waves = 2 hw-strips x {depth-role, tran-role}
__global__ __launch_bounds__(256, 4)
void fused_kernel(const float* __restrict__ x,
                  const float* __restrict__ dnet_b,
                  const unsigned short* __restrict__ w1d,
                  const unsigned short* __restrict__ w1t,
                  const unsigned short* __restrict__ projb,
                  const float* __restrict__ scale,
                  const float* __restrict__ shift,
                  float* __restrict__ out) {
    __shared__ __align__(16) unsigned short xs[32 * 256];       // 16 KB
    __shared__ __align__(16) unsigned short trs[2][16 * 128];   // 8 KB
    __shared__ float ss[2][16];
    __shared__ float biasd[96];
    __shared__ float biast[128];
    __shared__ float sc_s[256];
    __shared__ float sh_s[256];

    const int bid = blockIdx.x;
    const int n   = bid / NTILES;
    const int hw0 = (bid % NTILES) * TILE;
    const int t    = threadIdx.x;
    const int lane = t & 63;
    const int wv   = t >> 6;          // 0..3
    const int strip = wv >> 1;        // 0..1
    const int role  = wv & 1;         // 0=depth, 1=tran

    // ---- stage constants into LDS ----
    if (t < 96)       biasd[t] = (t < NDEPTH) ? dnet_b[t] : 0.f;
    else if (t < 224) biast[t - 96] = dnet_b[t - 8];   // dnet_b[88..215]
    sc_s[t] = scale[t];
    sh_s[t] = shift[t];

    // ---- stage x tile into LDS (transpose to [hw][c], bf16, swizzled) ----
    {
        const int hwl = t & 31;
        const int cg  = t >> 5;       // 0..7
        const float* xb = x + (size_t)n * C_IN * HW + hw0 + hwl;
        #pragma unroll
        for (int cb = 0; cb < 4; ++cb) {
            const int c0 = cb * 64 + cg * 8;
            float f[8];
            #pragma unroll
            for (int j = 0; j < 8; ++j) f[j] = xb[(size_t)(c0 + j) * HW];
            uint4 v;
            v.x = pack2(f[0], f[1]);
            v.y = pack2(f[2], f[3]);
            v.z = pack2(f[4], f[5]);
            v.w = pack2(f[6], f[7]);
            const int csw = (c0 >> 3) ^ (hwl & 7);
            *reinterpret_cast<uint4*>(&xs[hwl * 256 + csw * 8]) = v;
        }
    }
    __syncthreads();

    const int g = lane >> 4;          // 0..3
    const int m = lane & 15;
    const int brow  = strip * 16 + m;         // xs row this lane reads
    const int hwcol = hw0 + strip * 16 + m;   // global hw of this lane's D column

    if (role == 0) {
        // ================= depth wave =================
        f32x4 accd[6];
        #pragma unroll
        for (int i = 0; i < 6; ++i) accd[i] = (f32x4){0.f, 0.f, 0.f, 0.f};
        #pragma unroll
        for (int ks = 0; ks < 8; ++ks) {
            const int k0 = ks * 32;
            const int csw = ((k0 >> 3) + g) ^ (brow & 7);
            bf16x8 b = *reinterpret_cast<const bf16x8*>(&xs[brow * 256 + csw * 8]);
            #pragma unroll
            for (int dt = 0; dt < 6; ++dt) {
                bf16x8 a = *reinterpret_cast<const bf16x8*>(&w1d[(dt * 16 + m) * 256 + k0 + g * 8]);
                accd[dt] = __builtin_amdgcn_mfma_f32_16x16x32_bf16(a, b, accd[dt], 0, 0, 0);
            }
        }

        // softmax over depth bins (cross-lane ^16,^32 since col=lane&15)
        float dv[6][4], ev[6][4];
        float mx = -1e30f;
        #pragma unroll
        for (int dt = 0; dt < 6; ++dt) {
            #pragma unroll
            for (int r = 0; r < 4; ++r) {
                const int o = dt * 16 + g * 4 + r;
                float v = accd[dt][r] + biasd[o];
                dv[dt][r] = v;
                if (o < NDEPTH) mx = fmaxf(mx, v);
            }
        }
        mx = fmaxf(mx, __shfl_xor(mx, 16));
        mx = fmaxf(mx, __shfl_xor(mx, 32));
        float sum = 0.f;
        #pragma unroll
        for (int dt = 0; dt < 6; ++dt) {
            #pragma unroll
            for (int r = 0; r < 4; ++r) {
                const int o = dt * 16 + g * 4 + r;
                float e = (o < NDEPTH) ? __expf(dv[dt][r] - mx) : 0.f;
                ev[dt][r] = e;
                sum += e;
            }
        }
        sum += __shfl_xor(sum, 16);
        sum += __shfl_xor(sum, 32);
        const float inv = 1.0f / sum;

        float sp = 0.f;
        #pragma unroll
        for (int dt = 0; dt < 6; ++dt) {
            #pragma unroll
            for (int r = 0; r < 4; ++r) {
                const int o = dt * 16 + g * 4 + r;
                if (o < NDEPTH)
                    sp += ev[dt][r] * inv * ((1.f + (float)o * (44.f / 87.f)) * (1.f / 23.f));
            }
        }
        sp += __shfl_xor(sp, 16);
        sp += __shfl_xor(sp, 32);
        if (lane < 16) ss[strip][m] = sp;

        // stores of logits / prob
        float* lg = out + LOG_OFF  + (size_t)n * NDEPTH * HW + hwcol;
        float* pb = out + PROB_OFF + (size_t)n * NDEPTH * HW + hwcol;
        #pragma unroll
        for (int dt = 0; dt < 6; ++dt) {
            #pragma unroll
            for (int r = 0; r < 4; ++r) {
                const int o = dt * 16 + g * 4 + r;
                if (o < NDEPTH) {
                    lg[(size_t)o * HW] = dv[dt][r];
                    pb[(size_t)o * HW] = ev[dt][r] * inv;
                }
            }
        }
    } else {
        // ================= tran wave =================
        f32x4 acct[8];
        #pragma unroll
        for (int i = 0; i < 8; ++i) acct[i] = (f32x4){0.f, 0.f, 0.f, 0.f};
        #pragma unroll
        for (int ks = 0; ks < 8; ++ks) {
            const int k0 = ks * 32;
            const int csw = ((k0 >> 3) + g) ^ (brow & 7);
            bf16x8 b = *reinterpret_cast<const bf16x8*>(&xs[brow * 256 + csw * 8]);
            #pragma unroll
            for (int tt = 0; tt < 8; ++tt) {
                bf16x8 a = *reinterpret_cast<const bf16x8*>(&w1t[(tt * 16 + m) * 256 + k0 + g * 8]);
                acct[tt] = __builtin_amdgcn_mfma_f32_16x16x32_bf16(a, b, acct[tt], 0, 0, 0);
            }
        }
        // write tran (+bias) to per-strip LDS as bf16
        unsigned short* tw = &trs[strip][0];
        #pragma unroll
        for (int tt = 0; tt < 8; ++tt) {
            const int cb = tt * 16 + g * 4;
            float v0 = acct[tt][0] + biast[cb + 0];
            float v1 = acct[tt][1] + biast[cb + 1];
            float v2 = acct[tt][2] + biast[cb + 2];
            float v3 = acct[tt][3] + biast[cb + 3];
            const int csw = (cb >> 3) ^ (m & 7);
            uint2 pkd;
            pkd.x = pack2(v0, v1);
            pkd.y = pack2(v2, v3);
            *reinterpret_cast<uint2*>(&tw[m * 128 + csw * 8 + (g & 1) * 4]) = pkd;
        }
    }
    __syncthreads();

    // ---- GEMM2: each wave does 8 of 16 output-channel tiles for its strip ----
    f32x4 acc2[8];
    #pragma unroll
    for (int i = 0; i < 8; ++i) acc2[i] = (f32x4){0.f, 0.f, 0.f, 0.f};
    {
        const unsigned short* tw = &trs[strip][0];
        const int ctb = role * 8;
        #pragma unroll
        for (int ks = 0; ks < 4; ++ks) {
            const int k0 = ks * 32;
            const int csw = ((k0 >> 3) + g) ^ (m & 7);
            bf16x8 b = *reinterpret_cast<const bf16x8*>(&tw[m * 128 + csw * 8]);
            #pragma unroll
            for (int ct = 0; ct < 8; ++ct) {
                bf16x8 a = *reinterpret_cast<const bf16x8*>(&projb[((ctb + ct) * 16 + m) * 128 + k0 + g * 8]);
                acc2[ct] = __builtin_amdgcn_mfma_f32_16x16x32_bf16(a, b, acc2[ct], 0, 0, 0);
            }
        }
    }

    // ---- epilogue: BN + exact GELU + *s, store bev ----
    {
        const float sp = ss[strip][m];
        float* bev = out + (size_t)n * C_IN * HW + hwcol;
        const int ctb = role * 8;
        #pragma unroll
        for (int ct = 0; ct < 8; ++ct) {
            #pragma unroll
            for (int r = 0; r < 4; ++r) {
                const int cc = (ctb + ct) * 16 + g * 4 + r;
                float v  = acc2[ct][r] * sc_s[cc] + sh_s[cc];
                float ge = 0.5f * v * (1.f + erff(v * 0.70710678118f));
                bev[(size_t)cc * HW] = ge * sp;
            }
        }
    }
}

extern "C" void kernel_launch(void* const* d_in, const int* in_sizes, int n_in,
                              void* d_out, int out_size, void* d_ws, size_t ws_size,
                              hipStream_t stream) {
    const float* x      = (const float*)d_in[0];
    const float* dnet_w = (const float*)d_in[1];
    const float* dnet_b = (const float*)d_in[2];
    const float* proj_w = (const float*)d_in[3];
    const float* gamma  = (const float*)d_in[4];
    const float* beta   = (const float*)d_in[5];
    const float* mean   = (const float*)d_in[6];
    const float* var    = (const float*)d_in[7];
    float* out = (float*)d_out;

    char* ws = (char*)d_ws;
    unsigned short* w1d   = (unsigned short*)ws;                         // 96*256*2  = 49152 B
    unsigned short* w1t   = (unsigned short*)(ws + 49152);               // 128*256*2 = 65536 B
    unsigned short* projb = (unsigned short*)(ws + 49152 + 65536);       // 256*128*2 = 65536 B
    float* scale = (float*)(ws + 49152 + 65536 + 65536);
    float* shift = scale + 256;

    prep_kernel<<<96, 256, 0, stream>>>(dnet_w, proj_w, gamma, beta, mean, var,
                                        w1d, w1t, projb, scale, shift);
    fused_kernel<<<NB * NTILES, 256, 0, stream>>>(x, dnet_b, w1d, w1t, projb,
                                                  scale, shift, out);
}

// Round 4
// 155.408 us; speedup vs baseline: 1.2189x; 1.0358x over previous
//
#include <hip/hip_runtime.h>
#include <hip/hip_bf16.h>
#include <math.h>

#define C_IN 256
#define CC 128
#define NDEPTH 88
#define HW 2816            // 32*88
#define NB 12
#define TILE 32            // hw columns per workgroup (2 strips of 16)
#define NTILES 88          // 2816/32
#define LOG_OFF   ((size_t)8650752)   // 12*256*2816
#define PROB_OFF  ((size_t)11624448)  // + 12*88*2816

typedef __attribute__((ext_vector_type(8))) short bf16x8;
typedef __attribute__((ext_vector_type(4))) float f32x4;

__device__ __forceinline__ unsigned short f2bf(float f) {
    unsigned int u = __float_as_uint(f);
    unsigned int r = (u + 0x7fffu + ((u >> 16) & 1u)) >> 16;
    return (unsigned short)r;
}
__device__ __forceinline__ unsigned int pack2(float a, float b) {
    return (unsigned int)f2bf(a) | ((unsigned int)f2bf(b) << 16);
}
// barrier that only drains LDS ops (no vmcnt(0) store drain like __syncthreads)
__device__ __forceinline__ void bar_lgkm() {
    asm volatile("s_waitcnt lgkmcnt(0)\n\ts_barrier" ::: "memory");
}
// tanh-approx GELU in sigmoid form: x * sigmoid(1.595769x + 0.0713548x^3)
__device__ __forceinline__ float gelu_fast(float v) {
    float u = v * (1.5957691216f + 0.07135481283f * v * v);
    return v / (1.f + __expf(-u));
}

// ---------------- prep: weights->bf16 (padded), BN fold ----------------
__global__ void prep_kernel(const float* __restrict__ dnet_w,
                            const float* __restrict__ proj_w,
                            const float* __restrict__ gamma,
                            const float* __restrict__ beta,
                            const float* __restrict__ mean,
                            const float* __restrict__ var,
                            unsigned short* __restrict__ w1d,   // [96][256]
                            unsigned short* __restrict__ w1t,   // [128][256]
                            unsigned short* __restrict__ projb, // [256][128]
                            float* __restrict__ scale,
                            float* __restrict__ shift) {
    const int tid = blockIdx.x * blockDim.x + threadIdx.x;
    const int total = 96 * 256 + 128 * 256 + 256 * 128;
    for (int idx = tid; idx < total; idx += gridDim.x * blockDim.x) {
        if (idx < 96 * 256) {
            int o = idx >> 8, c = idx & 255;
            w1d[idx] = (o < NDEPTH) ? f2bf(dnet_w[o * 256 + c]) : (unsigned short)0;
        } else if (idx < 96 * 256 + 128 * 256) {
            int j = idx - 96 * 256;
            w1t[j] = f2bf(dnet_w[(NDEPTH + (j >> 8)) * 256 + (j & 255)]);
        } else {
            int j = idx - 96 * 256 - 128 * 256;
            projb[j] = f2bf(proj_w[j]);
        }
    }
    if (tid < 256) {
        float sc = gamma[tid] * rsqrtf(var[tid] + 1e-5f);
        scale[tid] = sc;
        shift[tid] = beta[tid] - mean[tid] * sc;
    }
}

// ---------------- fused main kernel ----------------
// 512 threads = 8 waves = {K-half 0, K-half 1} x 2 hw-strips x {depth, tran}
__global__ __launch_bounds__(512, 6)
void fused_kernel(const float* __restrict__ x,
                  const float* __restrict__ dnet_b,
                  const unsigned short* __restrict__ w1d,
                  const unsigned short* __restrict__ w1t,
                  const unsigned short* __restrict__ projb,
                  const float* __restrict__ scale,
                  const float* __restrict__ shift,
                  float* __restrict__ out) {
    // phase1: xs = x-tile [32 hw][256 c] bf16 swizzled (16 KB)
    // phase2: overlaid partial-sum buffer f32x4 part[2 strips][14 tiles][64 lanes] (28 KB)
    __shared__ __align__(16) char buf[28672];
    __shared__ __align__(16) unsigned short trs[2][16 * 128];   // 8 KB
    __shared__ float ss[2][16];
    __shared__ float biasd[96];
    __shared__ float biast[128];
    __shared__ float sc_s[256];
    __shared__ float sh_s[256];

    unsigned short* xs = (unsigned short*)buf;
    f32x4* part = (f32x4*)buf;

    const int bid = blockIdx.x;
    const int n   = bid / NTILES;
    const int hw0 = (bid % NTILES) * TILE;
    const int t    = threadIdx.x;
    const int lane = t & 63;
    const int wv   = t >> 6;          // 0..7
    const int khalf = wv >> 2;        // 0..1 (K range)
    const int sub   = wv & 3;
    const int strip = sub >> 1;       // 0..1
    const int role  = sub & 1;        // 0=depth, 1=tran

    // ---- stage constants into LDS ----
    if (t < 96)       biasd[t] = (t < NDEPTH) ? dnet_b[t] : 0.f;
    else if (t < 224) biast[t - 96] = dnet_b[t - 8];   // dnet_b[88..215]
    if (t < 256) { sc_s[t] = scale[t]; sh_s[t] = shift[t]; }

    // ---- stage x tile into LDS (transpose to [hw][c], bf16, swizzled) ----
    {
        const int hwl = t & 31;
        const int cg  = t >> 5;       // 0..15
        const float* xb = x + (size_t)n * C_IN * HW + hw0 + hwl;
        #pragma unroll
        for (int cb = 0; cb < 2; ++cb) {
            const int c0 = cb * 128 + cg * 8;
            float f[8];
            #pragma unroll
            for (int j = 0; j < 8; ++j) f[j] = xb[(size_t)(c0 + j) * HW];
            uint4 v;
            v.x = pack2(f[0], f[1]);
            v.y = pack2(f[2], f[3]);
            v.z = pack2(f[4], f[5]);
            v.w = pack2(f[6], f[7]);
            const int csw = (c0 >> 3) ^ (hwl & 7);
            *reinterpret_cast<uint4*>(&xs[hwl * 256 + csw * 8]) = v;
        }
    }
    bar_lgkm();

    const int g = lane >> 4;          // 0..3
    const int m = lane & 15;
    const int brow  = strip * 16 + m;         // xs row this lane reads
    const int hwcol = hw0 + strip * 16 + m;   // global hw of this lane's D column

    // ---- GEMM1 (this wave's K-half) + publish/reduce + middle stage ----
    if (role == 0) {
        f32x4 accd[6];
        #pragma unroll
        for (int i = 0; i < 6; ++i) accd[i] = (f32x4){0.f, 0.f, 0.f, 0.f};
        #pragma unroll
        for (int ksl = 0; ksl < 4; ++ksl) {
            const int k0 = (khalf * 4 + ksl) * 32;
            const int csw = ((k0 >> 3) + g) ^ (brow & 7);
            bf16x8 b = *reinterpret_cast<const bf16x8*>(&xs[brow * 256 + csw * 8]);
            #pragma unroll
            for (int dt = 0; dt < 6; ++dt) {
                bf16x8 a = *reinterpret_cast<const bf16x8*>(&w1d[(dt * 16 + m) * 256 + k0 + g * 8]);
                accd[dt] = __builtin_amdgcn_mfma_f32_16x16x32_bf16(a, b, accd[dt], 0, 0, 0);
            }
        }
        bar_lgkm();   // all xs reads done; region reusable
        if (khalf == 1) {
            #pragma unroll
            for (int dt = 0; dt < 6; ++dt)
                part[(strip * 14 + dt) * 64 + lane] = accd[dt];
        }
        bar_lgkm();
        if (khalf == 0) {
            #pragma unroll
            for (int dt = 0; dt < 6; ++dt)
                accd[dt] += part[(strip * 14 + dt) * 64 + lane];
            #pragma unroll
            for (int dt = 0; dt < 6; ++dt) {
                #pragma unroll
                for (int r = 0; r < 4; ++r)
                    accd[dt][r] += biasd[dt * 16 + g * 4 + r];
            }
            float mx = -1e30f;
            #pragma unroll
            for (int dt = 0; dt < 6; ++dt) {
                #pragma unroll
                for (int r = 0; r < 4; ++r) {
                    const int o = dt * 16 + g * 4 + r;
                    if (o < NDEPTH) mx = fmaxf(mx, accd[dt][r]);
                }
            }
            mx = fmaxf(mx, __shfl_xor(mx, 16));
            mx = fmaxf(mx, __shfl_xor(mx, 32));
            float sum = 0.f, spn = 0.f;
            #pragma unroll
            for (int dt = 0; dt < 6; ++dt) {
                #pragma unroll
                for (int r = 0; r < 4; ++r) {
                    const int o = dt * 16 + g * 4 + r;
                    if (o < NDEPTH) {
                        float e = __expf(accd[dt][r] - mx);
                        sum += e;
                        spn += e * ((1.f + (float)o * (44.f / 87.f)) * (1.f / 23.f));
                    }
                }
            }
            sum += __shfl_xor(sum, 16);
            sum += __shfl_xor(sum, 32);
            spn += __shfl_xor(spn, 16);
            spn += __shfl_xor(spn, 32);
            const float inv = 1.0f / sum;
            if (lane < 16) ss[strip][m] = spn * inv;
            float* lg = out + LOG_OFF  + (size_t)n * NDEPTH * HW + hwcol;
            float* pb = out + PROB_OFF + (size_t)n * NDEPTH * HW + hwcol;
            #pragma unroll
            for (int dt = 0; dt < 6; ++dt) {
                #pragma unroll
                for (int r = 0; r < 4; ++r) {
                    const int o = dt * 16 + g * 4 + r;
                    if (o < NDEPTH) {
                        lg[(size_t)o * HW] = accd[dt][r];
                        pb[(size_t)o * HW] = __expf(accd[dt][r] - mx) * inv;
                    }
                }
            }
        }
    } else {
        f32x4 acct[8];
        #pragma unroll
        for (int i = 0; i < 8; ++i) acct[i] = (f32x4){0.f, 0.f, 0.f, 0.f};
        #pragma unroll
        for (int ksl = 0; ksl < 4; ++ksl) {
            const int k0 = (khalf * 4 + ksl) * 32;
            const int csw = ((k0 >> 3) + g) ^ (brow & 7);
            bf16x8 b = *reinterpret_cast<const bf16x8*>(&xs[brow * 256 + csw * 8]);
            #pragma unroll
            for (int tt = 0; tt < 8; ++tt) {
                bf16x8 a = *reinterpret_cast<const bf16x8*>(&w1t[(tt * 16 + m) * 256 + k0 + g * 8]);
                acct[tt] = __builtin_amdgcn_mfma_f32_16x16x32_bf16(a, b, acct[tt], 0, 0, 0);
            }
        }
        bar_lgkm();   // all xs reads done; region reusable
        if (khalf == 1) {
            #pragma unroll
            for (int tt = 0; tt < 8; ++tt)
                part[(strip * 14 + 6 + tt) * 64 + lane] = acct[tt];
        }
        bar_lgkm();
        if (khalf == 0) {
            #pragma unroll
            for (int tt = 0; tt < 8; ++tt)
                acct[tt] += part[(strip * 14 + 6 + tt) * 64 + lane];
            unsigned short* tw = &trs[strip][0];
            #pragma unroll
            for (int tt = 0; tt < 8; ++tt) {
                const int cb = tt * 16 + g * 4;
                float v0 = acct[tt][0] + biast[cb + 0];
                float v1 = acct[tt][1] + biast[cb + 1];
                float v2 = acct[tt][2] + biast[cb + 2];
                float v3 = acct[tt][3] + biast[cb + 3];
                const int csw = (cb >> 3) ^ (m & 7);
                uint2 pkd;
                pkd.x = pack2(v0, v1);
                pkd.y = pack2(v2, v3);
                *reinterpret_cast<uint2*>(&tw[m * 128 + csw * 8 + (g & 1) * 4]) = pkd;
            }
        }
    }
    bar_lgkm();

    // ---- GEMM2: 8 waves x 4 output-channel tiles ----
    const int strip2 = wv >> 2;            // 0..1
    const int ctb    = (wv & 3) * 4;       // 0,4,8,12
    const int hwcol2 = hw0 + strip2 * 16 + m;
    f32x4 acc2[4];
    #pragma unroll
    for (int i = 0; i < 4; ++i) acc2[i] = (f32x4){0.f, 0.f, 0.f, 0.f};
    {
        const unsigned short* tw = &trs[strip2][0];
        #pragma unroll
        for (int ks = 0; ks < 4; ++ks) {
            const int k0 = ks * 32;
            const int csw = ((k0 >> 3) + g) ^ (m & 7);
            bf16x8 b = *reinterpret_cast<const bf16x8*>(&tw[m * 128 + csw * 8]);
            #pragma unroll
            for (int ct = 0; ct < 4; ++ct) {
                bf16x8 a = *reinterpret_cast<const bf16x8*>(&projb[((ctb + ct) * 16 + m) * 128 + k0 + g * 8]);
                acc2[ct] = __builtin_amdgcn_mfma_f32_16x16x32_bf16(a, b, acc2[ct], 0, 0, 0);
            }
        }
    }

    // ---- epilogue: BN + GELU + *s, store bev ----
    {
        const float sp = ss[strip2][m];
        float* bev = out + (size_t)n * C_IN * HW + hwcol2;
        #pragma unroll
        for (int ct = 0; ct < 4; ++ct) {
            #pragma unroll
            for (int r = 0; r < 4; ++r) {
                const int cc = (ctb + ct) * 16 + g * 4 + r;
                float v  = acc2[ct][r] * sc_s[cc] + sh_s[cc];
                bev[(size_t)cc * HW] = gelu_fast(v) * sp;
            }
        }
    }
}

extern "C" void kernel_launch(void* const* d_in, const int* in_sizes, int n_in,
                              void* d_out, int out_size, void* d_ws, size_t ws_size,
                              hipStream_t stream) {
    const float* x      = (const float*)d_in[0];
    const float* dnet_w = (const float*)d_in[1];
    const float* dnet_b = (const float*)d_in[2];
    const float* proj_w = (const float*)d_in[3];
    const float* gamma  = (const float*)d_in[4];
    const float* beta   = (const float*)d_in[5];
    const float* mean   = (const float*)d_in[6];
    const float* var    = (const float*)d_in[7];
    float* out = (float*)d_out;

    char* ws = (char*)d_ws;
    unsigned short* w1d   = (unsigned short*)ws;                         // 96*256*2  = 49152 B
    unsigned short* w1t   = (unsigned short*)(ws + 49152);               // 128*256*2 = 65536 B
    unsigned short* projb = (unsigned short*)(ws + 49152 + 65536);       // 256*128*2 = 65536 B
    float* scale = (float*)(ws + 49152 + 65536 + 65536);
    float* shift = scale + 256;

    prep_kernel<<<96, 256, 0, stream>>>(dnet_w, proj_w, gamma, beta, mean, var,
                                        w1d, w1t, projb, scale, shift);
    fused_kernel<<<NB * NTILES, 512, 0, stream>>>(x, dnet_b, w1d, w1t, projb,
                                                  scale, shift, out);
}

// Round 5
// 128.986 us; speedup vs baseline: 1.4686x; 1.2048x over previous
//
#include <hip/hip_runtime.h>
#include <hip/hip_bf16.h>
#include <math.h>

#define C_IN 256
#define CC 128
#define NDEPTH 88
#define HW 2816            // 32*88
#define NB 12
#define TILE 64            // hw columns per workgroup (4 strips of 16)
#define NTILES 44          // 2816/64
#define LOG_OFF   ((size_t)8650752)   // 12*256*2816
#define PROB_OFF  ((size_t)11624448)  // + 12*88*2816

typedef __attribute__((ext_vector_type(8))) short bf16x8;
typedef __attribute__((ext_vector_type(4))) float f32x4;

__device__ __forceinline__ unsigned short f2bf(float f) {
    unsigned int u = __float_as_uint(f);
    unsigned int r = (u + 0x7fffu + ((u >> 16) & 1u)) >> 16;
    return (unsigned short)r;
}
__device__ __forceinline__ unsigned int pack2(float a, float b) {
    return (unsigned int)f2bf(a) | ((unsigned int)f2bf(b) << 16);
}
// barrier that only drains LDS ops (no vmcnt(0) store drain like __syncthreads)
__device__ __forceinline__ void bar_lgkm() {
    asm volatile("s_waitcnt lgkmcnt(0)\n\ts_barrier" ::: "memory");
}
// tanh-approx GELU in sigmoid form
__device__ __forceinline__ float gelu_fast(float v) {
    float u = v * (1.5957691216f + 0.07135481283f * v * v);
    return v / (1.f + __expf(-u));
}

// ---------------- prep: weights -> bf16 in MFMA-fragment-major order ----------------
// w1df: 48 frags  [kh*24 + ks*6 + dt][lane]  (depth rows, zero-padded past 88)
// w1tf: 64 frags  [kh*32 + ks*8 + tt][lane]
// projf: 64 frags [ks*16 + ct][lane]
// each entry = 16 B = 8 bf16: orig[row(m)*K + k0 + g*8 .. +7], lane = g*16+m
__global__ void prep_kernel(const float* __restrict__ dnet_w,
                            const float* __restrict__ proj_w,
                            const float* __restrict__ gamma,
                            const float* __restrict__ beta,
                            const float* __restrict__ mean,
                            const float* __restrict__ var,
                            uint4* __restrict__ w1df,
                            uint4* __restrict__ w1tf,
                            uint4* __restrict__ projf,
                            float* __restrict__ scale,
                            float* __restrict__ shift) {
    const int tid = blockIdx.x * blockDim.x + threadIdx.x;
    const int N1 = 48 * 64, N2 = 64 * 64, N3 = 64 * 64;
    for (int e = tid; e < N1 + N2 + N3; e += gridDim.x * blockDim.x) {
        uint4 v = {0u, 0u, 0u, 0u};
        if (e < N1) {
            const int fb = e >> 6, l = e & 63;
            const int kh = fb / 24, rem = fb % 24, ks = rem / 6, dt = rem % 6;
            const int m = l & 15, g = l >> 4;
            const int o = dt * 16 + m;
            if (o < NDEPTH) {
                const float* p = dnet_w + o * 256 + kh * 128 + ks * 32 + g * 8;
                v.x = pack2(p[0], p[1]); v.y = pack2(p[2], p[3]);
                v.z = pack2(p[4], p[5]); v.w = pack2(p[6], p[7]);
            }
            w1df[e] = v;
        } else if (e < N1 + N2) {
            const int e2 = e - N1;
            const int fb = e2 >> 6, l = e2 & 63;
            const int kh = fb / 32, rem = fb % 32, ks = rem / 8, tt = rem % 8;
            const int m = l & 15, g = l >> 4;
            const float* p = dnet_w + (NDEPTH + tt * 16 + m) * 256 + kh * 128 + ks * 32 + g * 8;
            v.x = pack2(p[0], p[1]); v.y = pack2(p[2], p[3]);
            v.z = pack2(p[4], p[5]); v.w = pack2(p[6], p[7]);
            w1tf[e2] = v;
        } else {
            const int e3 = e - N1 - N2;
            const int fb = e3 >> 6, l = e3 & 63;
            const int ks = fb >> 4, ct = fb & 15;
            const int m = l & 15, g = l >> 4;
            const float* p = proj_w + (ct * 16 + m) * 128 + ks * 32 + g * 8;
            v.x = pack2(p[0], p[1]); v.y = pack2(p[2], p[3]);
            v.z = pack2(p[4], p[5]); v.w = pack2(p[6], p[7]);
            projf[e3] = v;
        }
    }
    if (tid < 256) {
        float sc = gamma[tid] * rsqrtf(var[tid] + 1e-5f);
        scale[tid] = sc;
        shift[tid] = beta[tid] - mean[tid] * sc;
    }
}

// ---------------- fused main kernel ----------------
// 512 threads = 8 waves = 4 hw-strips x 2 K-halves
__global__ __launch_bounds__(512, 4)
void fused_kernel(const float* __restrict__ x,
                  const float* __restrict__ dnet_b,
                  const uint4* __restrict__ w1df,
                  const uint4* __restrict__ w1tf,
                  const uint4* __restrict__ projf,
                  const float* __restrict__ scale,
                  const float* __restrict__ shift,
                  float* __restrict__ out) {
    // phase1: xs = x-tile [64 hw][256 c] bf16 swizzled (32 KB)
    // phase2 overlay: partD [4][6][64] f32x4 (24 KB) + partT [4][8][64] f32x4 (32 KB)
    __shared__ __align__(16) char buf[57344];
    __shared__ __align__(16) unsigned short trs[4][16 * 128];   // 16 KB
    __shared__ float ss[4][16];
    __shared__ float biasd[96];
    __shared__ float biast[128];
    __shared__ float sc_s[256];
    __shared__ float sh_s[256];

    unsigned short* xs = (unsigned short*)buf;
    f32x4* partD = (f32x4*)buf;                 // [strip][dt][lane]
    f32x4* partT = (f32x4*)(buf + 24576);       // [strip][tt][lane]

    const int bid = blockIdx.x;
    const int n   = bid / NTILES;
    const int hw0 = (bid % NTILES) * TILE;
    const int t     = threadIdx.x;
    const int lane  = t & 63;
    const int wv    = t >> 6;         // 0..7
    const int strip = wv & 3;         // 0..3
    const int khalf = wv >> 2;        // 0..1

    // ---- stage constants into LDS ----
    if (t < 96)       biasd[t] = (t < NDEPTH) ? dnet_b[t] : 0.f;
    else if (t < 224) biast[t - 96] = dnet_b[t - 8];   // dnet_b[88..215]
    if (t < 256) { sc_s[t] = scale[t]; sh_s[t] = shift[t]; }

    // ---- stage x tile into LDS (transpose to [hw][c], bf16, swizzled) ----
    {
        const int hwl = t & 63;
        const int cg  = t >> 6;       // 0..7
        const float* xb = x + (size_t)n * C_IN * HW + hw0 + hwl;
        #pragma unroll
        for (int cb = 0; cb < 4; ++cb) {
            const int c0 = cb * 64 + cg * 8;
            float f[8];
            #pragma unroll
            for (int j = 0; j < 8; ++j) f[j] = xb[(size_t)(c0 + j) * HW];
            uint4 v;
            v.x = pack2(f[0], f[1]);
            v.y = pack2(f[2], f[3]);
            v.z = pack2(f[4], f[5]);
            v.w = pack2(f[6], f[7]);
            const int csw = (c0 >> 3) ^ (hwl & 7);
            *reinterpret_cast<uint4*>(&xs[hwl * 256 + csw * 8]) = v;
        }
    }
    bar_lgkm();

    const int g = lane >> 4;          // 0..3
    const int m = lane & 15;
    const int brow  = strip * 16 + m;         // xs row this lane reads
    const int hwcol = hw0 + strip * 16 + m;   // global hw of this lane's D column

    // ---- GEMM1: this wave computes ALL 14 o-tiles for its (strip, khalf) ----
    f32x4 accd[6], acct[8];
    #pragma unroll
    for (int i = 0; i < 6; ++i) accd[i] = (f32x4){0.f, 0.f, 0.f, 0.f};
    #pragma unroll
    for (int i = 0; i < 8; ++i) acct[i] = (f32x4){0.f, 0.f, 0.f, 0.f};
    {
        const bf16x8* w1dv = (const bf16x8*)w1df;
        const bf16x8* w1tv = (const bf16x8*)w1tf;
        #pragma unroll
        for (int ksl = 0; ksl < 4; ++ksl) {
            const int k0 = (khalf * 4 + ksl) * 32;
            const int csw = ((k0 >> 3) + g) ^ (brow & 7);
            bf16x8 b = *reinterpret_cast<const bf16x8*>(&xs[brow * 256 + csw * 8]);
            #pragma unroll
            for (int dt = 0; dt < 6; ++dt) {
                bf16x8 a = w1dv[((khalf * 4 + ksl) * 6 + dt) * 64 + lane];
                accd[dt] = __builtin_amdgcn_mfma_f32_16x16x32_bf16(a, b, accd[dt], 0, 0, 0);
            }
            #pragma unroll
            for (int tt = 0; tt < 8; ++tt) {
                bf16x8 a = w1tv[((khalf * 4 + ksl) * 8 + tt) * 64 + lane];
                acct[tt] = __builtin_amdgcn_mfma_f32_16x16x32_bf16(a, b, acct[tt], 0, 0, 0);
            }
        }
    }
    bar_lgkm();   // all xs reads done; region reusable for partials

    // ---- publish the half this wave will NOT finish ----
    if (khalf == 0) {
        #pragma unroll
        for (int tt = 0; tt < 8; ++tt)
            partT[(strip * 8 + tt) * 64 + lane] = acct[tt];
    } else {
        #pragma unroll
        for (int dt = 0; dt < 6; ++dt)
            partD[(strip * 6 + dt) * 64 + lane] = accd[dt];
    }
    bar_lgkm();

    // ---- middle stage: khalf0 -> depth softmax; khalf1 -> tran + trs ----
    float mx = 0.f, inv = 0.f;   // live into deferred stores (khalf0)
    if (khalf == 0) {
        #pragma unroll
        for (int dt = 0; dt < 6; ++dt) {
            accd[dt] += partD[(strip * 6 + dt) * 64 + lane];
            #pragma unroll
            for (int r = 0; r < 4; ++r)
                accd[dt][r] += biasd[dt * 16 + g * 4 + r];
        }
        mx = -1e30f;
        #pragma unroll
        for (int dt = 0; dt < 6; ++dt) {
            #pragma unroll
            for (int r = 0; r < 4; ++r) {
                const int o = dt * 16 + g * 4 + r;
                if (o < NDEPTH) mx = fmaxf(mx, accd[dt][r]);
            }
        }
        mx = fmaxf(mx, __shfl_xor(mx, 16));
        mx = fmaxf(mx, __shfl_xor(mx, 32));
        float sum = 0.f, spn = 0.f;
        #pragma unroll
        for (int dt = 0; dt < 6; ++dt) {
            #pragma unroll
            for (int r = 0; r < 4; ++r) {
                const int o = dt * 16 + g * 4 + r;
                if (o < NDEPTH) {
                    float e = __expf(accd[dt][r] - mx);
                    sum += e;
                    spn += e * ((1.f + (float)o * (44.f / 87.f)) * (1.f / 23.f));
                }
            }
        }
        sum += __shfl_xor(sum, 16);
        sum += __shfl_xor(sum, 32);
        spn += __shfl_xor(spn, 16);
        spn += __shfl_xor(spn, 32);
        inv = 1.0f / sum;
        if (lane < 16) ss[strip][m] = spn * inv;
    } else {
        #pragma unroll
        for (int tt = 0; tt < 8; ++tt)
            acct[tt] += partT[(strip * 8 + tt) * 64 + lane];
        unsigned short* tw = &trs[strip][0];
        #pragma unroll
        for (int tt = 0; tt < 8; ++tt) {
            const int cb = tt * 16 + g * 4;
            float v0 = acct[tt][0] + biast[cb + 0];
            float v1 = acct[tt][1] + biast[cb + 1];
            float v2 = acct[tt][2] + biast[cb + 2];
            float v3 = acct[tt][3] + biast[cb + 3];
            const int csw = (cb >> 3) ^ (m & 7);
            uint2 pkd;
            pkd.x = pack2(v0, v1);
            pkd.y = pack2(v2, v3);
            *reinterpret_cast<uint2*>(&tw[m * 128 + csw * 8 + (g & 1) * 4]) = pkd;
        }
    }
    bar_lgkm();

    // ---- GEMM2: wave does 8 output-channel tiles (ctb) for its strip ----
    const int ctb = khalf * 8;
    f32x4 acc2[8];
    #pragma unroll
    for (int i = 0; i < 8; ++i) acc2[i] = (f32x4){0.f, 0.f, 0.f, 0.f};
    {
        const bf16x8* pv = (const bf16x8*)projf;
        const unsigned short* tw = &trs[strip][0];
        #pragma unroll
        for (int ks = 0; ks < 4; ++ks) {
            const int k0 = ks * 32;
            const int csw = ((k0 >> 3) + g) ^ (m & 7);
            bf16x8 b = *reinterpret_cast<const bf16x8*>(&tw[m * 128 + csw * 8]);
            #pragma unroll
            for (int ct = 0; ct < 8; ++ct) {
                bf16x8 a = pv[(ks * 16 + ctb + ct) * 64 + lane];
                acc2[ct] = __builtin_amdgcn_mfma_f32_16x16x32_bf16(a, b, acc2[ct], 0, 0, 0);
            }
        }
    }

    // ---- epilogue: BN + GELU + *s, store bev ----
    {
        const float sp = ss[strip][m];
        float* bev = out + (size_t)n * C_IN * HW + hwcol;
        #pragma unroll
        for (int ct = 0; ct < 8; ++ct) {
            #pragma unroll
            for (int r = 0; r < 4; ++r) {
                const int cc = (ctb + ct) * 16 + g * 4 + r;
                float v  = acc2[ct][r] * sc_s[cc] + sh_s[cc];
                bev[(size_t)cc * HW] = gelu_fast(v) * sp;
            }
        }
    }

    // ---- deferred logits/prob stores (khalf0; off the barrier path) ----
    if (khalf == 0) {
        float* lg = out + LOG_OFF  + (size_t)n * NDEPTH * HW + hwcol;
        float* pb = out + PROB_OFF + (size_t)n * NDEPTH * HW + hwcol;
        #pragma unroll
        for (int dt = 0; dt < 6; ++dt) {
            #pragma unroll
            for (int r = 0; r < 4; ++r) {
                const int o = dt * 16 + g * 4 + r;
                if (o < NDEPTH) {
                    lg[(size_t)o * HW] = accd[dt][r];
                    pb[(size_t)o * HW] = __expf(accd[dt][r] - mx) * inv;
                }
            }
        }
    }
}

extern "C" void kernel_launch(void* const* d_in, const int* in_sizes, int n_in,
                              void* d_out, int out_size, void* d_ws, size_t ws_size,
                              hipStream_t stream) {
    const float* x      = (const float*)d_in[0];
    const float* dnet_w = (const float*)d_in[1];
    const float* dnet_b = (const float*)d_in[2];
    const float* proj_w = (const float*)d_in[3];
    const float* gamma  = (const float*)d_in[4];
    const float* beta   = (const float*)d_in[5];
    const float* mean   = (const float*)d_in[6];
    const float* var    = (const float*)d_in[7];
    float* out = (float*)d_out;

    char* ws = (char*)d_ws;
    uint4* w1df = (uint4*)ws;                          // 48*64*16  = 49152 B
    uint4* w1tf = (uint4*)(ws + 49152);                // 64*64*16  = 65536 B
    uint4* projf = (uint4*)(ws + 49152 + 65536);       // 64*64*16  = 65536 B
    float* scale = (float*)(ws + 49152 + 65536 + 65536);
    float* shift = scale + 256;

    prep_kernel<<<96, 256, 0, stream>>>(dnet_w, proj_w, gamma, beta, mean, var,
                                        w1df, w1tf, projf, scale, shift);
    fused_kernel<<<NB * NTILES, 512, 0, stream>>>(x, dnet_b, w1df, w1tf, projf,
                                                  scale, shift, out);
}